// Round 1
// baseline (90.055 us; speedup 1.0000x reference)
//
#include <hip/hip_runtime.h>
#include <hip/hip_bf16.h>

#define VOCAB 100000
#define DIM   128
#define BATCH 4096
#define ROWS  16   // batch rows per block

using f32x4  = __attribute__((ext_vector_type(4))) float;
using bf16x8 = __attribute__((ext_vector_type(8))) short;

__device__ __forceinline__ unsigned short f2bf(float f) {
    union { float f; unsigned int u; } v; v.f = f;
    unsigned int r = v.u + 0x7FFF + ((v.u >> 16) & 1);   // round-to-nearest-even
    return (unsigned short)(r >> 16);
}

// LDS layout (bytes):
//   A tile : [0, 4096)    = 16 rows x 256B (128 bf16), XOR-swizzled
//   B tile : [4096, 36864) = W2^T, 128 rows (n) x 256B (128 bf16 over k), XOR-swizzled
// swizzle: byte_in_row ^= (row & 7) << 4   (flips bits 4..6; 16B blocks stay intact)

__global__ __launch_bounds__(256, 4)
void onehot_fc_kernel(const int* __restrict__ x,
                      const float* __restrict__ W1,
                      const float* __restrict__ b1,
                      const float* __restrict__ W2,
                      const float* __restrict__ b2,
                      float* __restrict__ out)
{
    __shared__ __align__(16) unsigned char lds[4096 + 32768];
    const int t   = threadIdx.x;
    const int blk = blockIdx.x;

    // ---- Phase 1: gather + bias + relu -> bf16 A tile ----
    {
        const int r = t >> 4;            // 0..15  (row within tile)
        const int c = (t & 15) * 8;      // 0..120 (col base, 8 floats per thread)
        const int grow = x[blk * ROWS + r];
        const float4 v0 = *(const float4*)(W1 + (size_t)grow * DIM + c);
        const float4 v1 = *(const float4*)(W1 + (size_t)grow * DIM + c + 4);
        const float4 g0 = *(const float4*)(b1 + c);
        const float4 g1 = *(const float4*)(b1 + c + 4);
        float h[8] = { v0.x + g0.x, v0.y + g0.y, v0.z + g0.z, v0.w + g0.w,
                       v1.x + g1.x, v1.y + g1.y, v1.z + g1.z, v1.w + g1.w };
        unsigned int p[4];
#pragma unroll
        for (int j = 0; j < 4; ++j) {
            const float a0 = fmaxf(h[2 * j], 0.f);
            const float a1 = fmaxf(h[2 * j + 1], 0.f);
            p[j] = (unsigned int)f2bf(a0) | ((unsigned int)f2bf(a1) << 16);
        }
        const int byte = r * 256 + ((c * 2) ^ ((r & 7) << 4));
        *(uint4*)(lds + byte) = make_uint4(p[0], p[1], p[2], p[3]);
    }

    // ---- Phase 2: stage W2^T as bf16 (swizzled) ----
    {
        const int nq = (t & 31) * 4;     // 4 consecutive n columns
        const int kc = (t >> 5) * 16;    // 16 consecutive k values
        unsigned int pk[4][8];
#pragma unroll
        for (int kk = 0; kk < 16; ++kk) {
            const float4 v = *(const float4*)(W2 + (size_t)(kc + kk) * DIM + nq);
            const unsigned short hh0 = f2bf(v.x), hh1 = f2bf(v.y),
                                 hh2 = f2bf(v.z), hh3 = f2bf(v.w);
            if (kk & 1) {
                pk[0][kk >> 1] |= (unsigned int)hh0 << 16;
                pk[1][kk >> 1] |= (unsigned int)hh1 << 16;
                pk[2][kk >> 1] |= (unsigned int)hh2 << 16;
                pk[3][kk >> 1] |= (unsigned int)hh3 << 16;
            } else {
                pk[0][kk >> 1] = (unsigned int)hh0;
                pk[1][kk >> 1] = (unsigned int)hh1;
                pk[2][kk >> 1] = (unsigned int)hh2;
                pk[3][kk >> 1] = (unsigned int)hh3;
            }
        }
#pragma unroll
        for (int j = 0; j < 4; ++j) {
            const int n    = nq + j;
            const int base = 4096 + n * 256;
            const int swz  = (n & 7) << 4;
            *(uint4*)(lds + base + ((kc * 2)      ^ swz)) =
                make_uint4(pk[j][0], pk[j][1], pk[j][2], pk[j][3]);
            *(uint4*)(lds + base + ((kc * 2 + 16) ^ swz)) =
                make_uint4(pk[j][4], pk[j][5], pk[j][6], pk[j][7]);
        }
    }
    __syncthreads();

    // ---- Phase 3: MFMA  h[16x128] @ W2[128x128] ----
    const int lane = t & 63;
    const int wave = t >> 6;            // 0..3, owns N-tiles {2w, 2w+1}
    const int l16  = lane & 15;
    const int lq   = lane >> 4;         // 0..3
    const int rA   = l16;               // A row (M=16)
    const int n0   = (wave * 2)     * 16 + l16;
    const int n1   = (wave * 2 + 1) * 16 + l16;

    f32x4 acc0 = {0.f, 0.f, 0.f, 0.f};
    f32x4 acc1 = {0.f, 0.f, 0.f, 0.f};
#pragma unroll
    for (int ks = 0; ks < 4; ++ks) {
        const int kb = ks * 64 + lq * 16;   // byte offset of this lane's k-chunk
        bf16x8 a  = *(bf16x8*)(lds +        rA * 256 + (kb ^ ((rA & 7) << 4)));
        bf16x8 bf0 = *(bf16x8*)(lds + 4096 + n0 * 256 + (kb ^ ((n0 & 7) << 4)));
        bf16x8 bf1 = *(bf16x8*)(lds + 4096 + n1 * 256 + (kb ^ ((n1 & 7) << 4)));
        acc0 = __builtin_amdgcn_mfma_f32_16x16x32_bf16(a, bf0, acc0, 0, 0, 0);
        acc1 = __builtin_amdgcn_mfma_f32_16x16x32_bf16(a, bf1, acc1, 0, 0, 0);
    }

    // ---- Epilogue: + b2, store fp32 ----
    const float bias0 = b2[n0];
    const float bias1 = b2[n1];
    float* orow = out + (size_t)blk * ROWS * DIM;
#pragma unroll
    for (int i = 0; i < 4; ++i) {
        const int r = lq * 4 + i;       // C/D row = 4*(lane>>4) + reg
        orow[r * DIM + n0] = acc0[i] + bias0;
        orow[r * DIM + n1] = acc1[i] + bias1;
    }
}

extern "C" void kernel_launch(void* const* d_in, const int* in_sizes, int n_in,
                              void* d_out, int out_size, void* d_ws, size_t ws_size,
                              hipStream_t stream) {
    const int*   x  = (const int*)d_in[0];
    const float* W1 = (const float*)d_in[1];
    const float* b1 = (const float*)d_in[2];
    const float* W2 = (const float*)d_in[3];
    const float* b2 = (const float*)d_in[4];
    float* out = (float*)d_out;
    hipLaunchKernelGGL(onehot_fc_kernel, dim3(BATCH / ROWS), dim3(256), 0, stream,
                       x, W1, b1, W2, b2, out);
}

// Round 2
// 88.934 us; speedup vs baseline: 1.0126x; 1.0126x over previous
//
#include <hip/hip_runtime.h>
#include <hip/hip_bf16.h>

#define VOCAB 100000
#define DIM   128
#define BATCH 4096
#define ROWS  16   // batch rows per block

using f32x4  = __attribute__((ext_vector_type(4))) float;
using bf16x8 = __attribute__((ext_vector_type(8))) short;

// compiler lowers paired __float2bfloat16 casts to v_cvt_pk_bf16_f32 (m240)
__device__ __forceinline__ unsigned int pack2(float lo, float hi) {
    const unsigned short l = __bfloat16_as_ushort(__float2bfloat16(lo));
    const unsigned short h = __bfloat16_as_ushort(__float2bfloat16(hi));
    return (unsigned int)l | ((unsigned int)h << 16);
}

// LDS layout (bytes):
//   A tile : [0, 4096)     = 16 rows x 256B (128 bf16), XOR-swizzled
//   B tile : [4096, 36864) = W2^T, 128 n-rows x 256B (128 bf16 over k), XOR-swizzled
// swizzle: byte_in_row ^= (row & 7) << 4   (flips bits 4..6; 16B blocks intact)

__global__ __launch_bounds__(256, 2)
void onehot_fc_kernel(const int* __restrict__ x,
                      const float* __restrict__ W1,
                      const float* __restrict__ b1,
                      const float* __restrict__ W2,
                      const float* __restrict__ b2,
                      float* __restrict__ out)
{
    __shared__ __align__(16) unsigned char lds[4096 + 32768];
    const int t   = threadIdx.x;
    const int blk = blockIdx.x;

    // ---- issue order matters: vmcnt retires in issue order ----
    // 1) x (head of the longest chain: x -> W1 -> pack -> LDS -> MFMA)
    const int r    = t >> 4;            // A row 0..15
    const int cb   = (t & 15) * 8;      // A col base (8 floats)
    const int grow = x[blk * ROWS + r];

    // 2) W2 loads (independent of x; 16 float4, coalesced across the wave)
    const int nq = (t & 31) * 4;        // 4 consecutive n columns
    const int kc = (t >> 5) * 16;       // 16 consecutive k values
    f32x4 w[16];
#pragma unroll
    for (int kk = 0; kk < 16; ++kk)
        w[kk] = *(const f32x4*)(W2 + (size_t)(kc + kk) * DIM + nq);

    // 3) b1 (independent)
    const f32x4 g0 = *(const f32x4*)(b1 + cb);
    const f32x4 g1 = *(const f32x4*)(b1 + cb + 4);

    // 4) W1 gather (depends on x; HBM-latency load stays in flight while
    //    W2 packing below proceeds — W2 was issued first so its vmcnt
    //    wait does not cover these)
    const f32x4 v0 = *(const f32x4*)(W1 + (size_t)grow * DIM + cb);
    const f32x4 v1 = *(const f32x4*)(W1 + (size_t)grow * DIM + cb + 4);

    // ---- W2 pack + store (swizzled W2^T bf16) ----
#pragma unroll
    for (int j = 0; j < 4; ++j) {
        const int n    = nq + j;
        const int base = 4096 + n * 256;
        const int swz  = (n & 7) << 4;
        uint4 q0, q1;
        q0.x = pack2(w[0][j],  w[1][j]);
        q0.y = pack2(w[2][j],  w[3][j]);
        q0.z = pack2(w[4][j],  w[5][j]);
        q0.w = pack2(w[6][j],  w[7][j]);
        q1.x = pack2(w[8][j],  w[9][j]);
        q1.y = pack2(w[10][j], w[11][j]);
        q1.z = pack2(w[12][j], w[13][j]);
        q1.w = pack2(w[14][j], w[15][j]);
        *(uint4*)(lds + base + ((kc * 2)      ^ swz)) = q0;
        *(uint4*)(lds + base + ((kc * 2 + 16) ^ swz)) = q1;
    }

    // ---- A tile: +b1, relu, bf16, swizzled store ----
    {
        uint4 qa;
        qa.x = pack2(fmaxf(v0[0] + g0[0], 0.f), fmaxf(v0[1] + g0[1], 0.f));
        qa.y = pack2(fmaxf(v0[2] + g0[2], 0.f), fmaxf(v0[3] + g0[3], 0.f));
        qa.z = pack2(fmaxf(v1[0] + g1[0], 0.f), fmaxf(v1[1] + g1[1], 0.f));
        qa.w = pack2(fmaxf(v1[2] + g1[2], 0.f), fmaxf(v1[3] + g1[3], 0.f));
        *(uint4*)(lds + r * 256 + ((cb * 2) ^ ((r & 7) << 4))) = qa;
    }
    __syncthreads();

    // ---- MFMA: h[16x128] @ W2[128x128] ----
    const int lane = t & 63;
    const int wave = t >> 6;            // 0..3, owns N-tiles {2w, 2w+1}
    const int l16  = lane & 15;
    const int lq   = lane >> 4;         // 0..3
    const int n0   = (wave * 2)     * 16 + l16;
    const int n1   = (wave * 2 + 1) * 16 + l16;

    f32x4 acc0 = {0.f, 0.f, 0.f, 0.f};
    f32x4 acc1 = {0.f, 0.f, 0.f, 0.f};
#pragma unroll
    for (int ks = 0; ks < 4; ++ks) {
        const int kb = ks * 64 + lq * 16;   // byte offset of this lane's k-chunk
        bf16x8 a   = *(bf16x8*)(lds +        l16 * 256 + (kb ^ ((l16 & 7) << 4)));
        bf16x8 bf0 = *(bf16x8*)(lds + 4096 + n0  * 256 + (kb ^ ((n0  & 7) << 4)));
        bf16x8 bf1 = *(bf16x8*)(lds + 4096 + n1  * 256 + (kb ^ ((n1  & 7) << 4)));
        acc0 = __builtin_amdgcn_mfma_f32_16x16x32_bf16(a, bf0, acc0, 0, 0, 0);
        acc1 = __builtin_amdgcn_mfma_f32_16x16x32_bf16(a, bf1, acc1, 0, 0, 0);
    }

    // ---- Epilogue: + b2, store fp32 ----
    const float bias0 = b2[n0];
    const float bias1 = b2[n1];
    float* orow = out + (size_t)blk * ROWS * DIM;
#pragma unroll
    for (int i = 0; i < 4; ++i) {
        const int rr = lq * 4 + i;      // C/D row = 4*(lane>>4) + reg
        orow[rr * DIM + n0] = acc0[i] + bias0;
        orow[rr * DIM + n1] = acc1[i] + bias1;
    }
}

extern "C" void kernel_launch(void* const* d_in, const int* in_sizes, int n_in,
                              void* d_out, int out_size, void* d_ws, size_t ws_size,
                              hipStream_t stream) {
    const int*   x  = (const int*)d_in[0];
    const float* W1 = (const float*)d_in[1];
    const float* b1 = (const float*)d_in[2];
    const float* W2 = (const float*)d_in[3];
    const float* b2 = (const float*)d_in[4];
    float* out = (float*)d_out;
    hipLaunchKernelGGL(onehot_fc_kernel, dim3(BATCH / ROWS), dim3(256), 0, stream,
                       x, W1, b1, W2, b2, out);
}